// Round 3
// baseline (951.716 us; speedup 1.0000x reference)
//
#include <hip/hip_runtime.h>
#include <stdint.h>

// Problem constants: N_S=8192, N_H=64, C=64
#define NSQ 8192

// Workspace layout (float offsets). Total ~4.06 MB.
#define WS_X1T  0u                                 // X1^T [64][8192]
#define WS_X2T  (64u * 8192u)                      // X2^T [64][8192]
#define WS_RS   (2u * 64u * 8192u)                 // rowsum [8192]
#define WS_W2T  (2u * 64u * 8192u + 8192u)         // W2^T [64][64]
#define WS_FLAG (2u * 64u * 8192u + 8192u + 4096u) // 1 uint: mask-dtype flag

// ---------------------------------------------------------------------------
// init: zero rowsum + flag, build W2T (W2T[h*64+i] = W2[i*64+h])
__global__ __launch_bounds__(256) void k_init(const float* __restrict__ W2,
                                              float* __restrict__ ws) {
    int t = threadIdx.x, b = blockIdx.x;
    ws[WS_RS + b * 256 + t] = 0.0f;   // 32 blocks x 256 = 8192
    if (b == 0) {
#pragma unroll
        for (int q = 0; q < 16; ++q) {
            int e = q * 256 + t;
            int i = e >> 6, h = e & 63;
            ws[WS_W2T + h * 64 + i] = W2[i * 64 + h];
        }
        if (t == 0) ((unsigned*)ws)[WS_FLAG] = 0u;
    }
}

// ---------------------------------------------------------------------------
// detect mask dtype from a 4 MB sample (1% density -> thousands of nonzeros
// in any candidate layout; false-negative probability ~0).
// f32 mask -> words == 0x3f800000 ; u8 packed -> some word > 1 ; i32 -> {0,1}
__global__ __launch_bounds__(256) void k_detect(const uint4* __restrict__ m,
                                                unsigned* __restrict__ flag) {
    __shared__ unsigned bf;
    int t = threadIdx.x;
    if (t == 0) bf = 0u;
    __syncthreads();
    size_t idx = (size_t)blockIdx.x * 256 + t;
    uint4 v = m[idx];
    unsigned a[4] = {v.x, v.y, v.z, v.w};
    unsigned lf = 0u;
#pragma unroll
    for (int q = 0; q < 4; ++q) {
        if (a[q] == 0x3f800000u) lf |= 2u;
        else if (a[q] > 1u)      lf |= 1u;
    }
    if (lf) atomicOr(&bf, lf);
    __syncthreads();
    if (t == 0 && bf) atomicOr(flag, bf);
}

// ---------------------------------------------------------------------------
// fused prep: reads H' ONCE (float4), computes
//   Y[s,h]  = sum_c H'[s,c,h]*w1[c]          (wave shuffle-reduce over c-groups)
//   X1[s,i] = sum_h Y[s,h]*W2[i,h]           -> X1T[i*8192+s]
//   X2[s,c] = sum_h H'[s,c,h]*w3[h]          -> X2T[c*8192+s]
__global__ __launch_bounds__(256) void k_prep(const float* __restrict__ H,
                                              const float* __restrict__ w1,
                                              const float* __restrict__ w3,
                                              const float* __restrict__ w2t,
                                              float* __restrict__ X1T,
                                              float* __restrict__ X2T) {
    __shared__ float ylds[4][64];
    int t = threadIdx.x;
    int sl = t >> 6, l = t & 63;
    int cq = l >> 4, hq = l & 15;
    size_t s = (size_t)blockIdx.x * 4 + sl;
    const float* hp = H + s * 4096;
    float4 w3q = *(const float4*)(w3 + hq * 4);
    float4 yacc = make_float4(0.f, 0.f, 0.f, 0.f);
    float x2p[16];
#pragma unroll
    for (int cc = 0; cc < 16; ++cc) {
        int c = cq * 16 + cc;
        float4 hv = *(const float4*)(hp + c * 64 + hq * 4);
        float wc = w1[c];
        yacc.x = fmaf(hv.x, wc, yacc.x);
        yacc.y = fmaf(hv.y, wc, yacc.y);
        yacc.z = fmaf(hv.z, wc, yacc.z);
        yacc.w = fmaf(hv.w, wc, yacc.w);
        x2p[cc] = hv.x * w3q.x + hv.y * w3q.y + hv.z * w3q.z + hv.w * w3q.w;
    }
#pragma unroll
    for (int cc = 0; cc < 16; ++cc) {
        float v = x2p[cc];
        v += __shfl_xor(v, 1);
        v += __shfl_xor(v, 2);
        v += __shfl_xor(v, 4);
        v += __shfl_xor(v, 8);
        x2p[cc] = v;
    }
    if (hq == 0) {
#pragma unroll
        for (int cc = 0; cc < 16; ++cc)
            X2T[(size_t)(cq * 16 + cc) * NSQ + s] = x2p[cc];
    }
    yacc.x += __shfl_xor(yacc.x, 16); yacc.x += __shfl_xor(yacc.x, 32);
    yacc.y += __shfl_xor(yacc.y, 16); yacc.y += __shfl_xor(yacc.y, 32);
    yacc.z += __shfl_xor(yacc.z, 16); yacc.z += __shfl_xor(yacc.z, 32);
    yacc.w += __shfl_xor(yacc.w, 16); yacc.w += __shfl_xor(yacc.w, 32);
    if (cq == 0) *(float4*)&ylds[sl][hq * 4] = yacc;
    __syncthreads();
    float a1 = 0.f;
    int i = l;
#pragma unroll
    for (int h = 0; h < 64; ++h) a1 = fmaf(ylds[sl][h], w2t[h * 64 + i], a1);
    X1T[(size_t)i * NSQ + s] = a1;
}

// ---------------------------------------------------------------------------
// main: 128x64 tile per block, 8x4 micro-tile (acc=32 regs, not 64, so the
// unified VGPR+AGPR footprint allows ~5 blocks/CU; LDS 24 KB). K staged in
// two 32-deep phases. Epilogue software-pipelined: loads for row i+1 issued
// before computing row i so V/B/mask misses overlap.
__global__ __launch_bounds__(256, 5) void k_main(const float* __restrict__ X1T,
                                                 const float* __restrict__ X2T,
                                                 const float* __restrict__ V,
                                                 const float* __restrict__ Bm,
                                                 const void* __restrict__ mask,
                                                 const unsigned* __restrict__ flag,
                                                 float* __restrict__ out,
                                                 float* __restrict__ rowsum) {
    __shared__ float as_[32 * 128];
    __shared__ float bs_[32 * 64];
    int t = threadIdx.x;
    int tx = t & 15, ty = t >> 4;
    int rowBase = blockIdx.y * 128;
    int colBase = blockIdx.x * 64;

    float acc[8][4];
#pragma unroll
    for (int i = 0; i < 8; ++i)
#pragma unroll
        for (int j = 0; j < 4; ++j) acc[i][j] = 0.f;

#pragma unroll
    for (int phase = 0; phase < 2; ++phase) {
        int kbase = phase * 32;
        if (phase) __syncthreads();
        // A: 1024 float4 (32k x 128m), B: 512 float4 (32k x 64n)
#pragma unroll
        for (int it = 0; it < 4; ++it) {
            int f4 = it * 256 + t;
            int k  = f4 >> 5;
            int mq = (f4 & 31) * 4;
            *(float4*)&as_[k * 128 + mq] =
                *(const float4*)(X1T + (size_t)(kbase + k) * NSQ + rowBase + mq);
        }
#pragma unroll
        for (int it = 0; it < 2; ++it) {
            int g = it * 256 + t;
            int k = g >> 4;
            int nq = (g & 15) * 4;
            *(float4*)&bs_[k * 64 + nq] =
                *(const float4*)(X2T + (size_t)(kbase + k) * NSQ + colBase + nq);
        }
        __syncthreads();

#pragma unroll 4
        for (int k = 0; k < 32; ++k) {
            float4 a0 = *(const float4*)&as_[k * 128 + ty * 8];
            float4 a1 = *(const float4*)&as_[k * 128 + ty * 8 + 4];
            float4 b0 = *(const float4*)&bs_[k * 64 + tx * 4];
            float am[8] = {a0.x, a0.y, a0.z, a0.w, a1.x, a1.y, a1.z, a1.w};
            float bn[4] = {b0.x, b0.y, b0.z, b0.w};
#pragma unroll
            for (int i = 0; i < 8; ++i)
#pragma unroll
                for (int j = 0; j < 4; ++j) acc[i][j] = fmaf(am[i], bn[j], acc[i][j]);
        }
    }

    unsigned fl = *flag;
    size_t colOff = (size_t)colBase + tx * 4;

    // pipelined epilogue: current-row regs
    float4 vC, bC; uint4 mC = {0,0,0,0}; unsigned u8C = 0;
    {
        size_t base = (size_t)(rowBase + ty * 8) * NSQ + colOff;
        vC = *(const float4*)(V + base);
        bC = *(const float4*)(Bm + base);
        if (fl & 1u) u8C = *(const unsigned*)((const uint8_t*)mask + base);
        else         mC  = *(const uint4*)((const unsigned*)mask + base);
    }
#pragma unroll
    for (int i = 0; i < 8; ++i) {
        float4 vN, bN; uint4 mN = {0,0,0,0}; unsigned u8N = 0;
        if (i < 7) {
            size_t nb = (size_t)(rowBase + ty * 8 + i + 1) * NSQ + colOff;
            vN = *(const float4*)(V + nb);
            bN = *(const float4*)(Bm + nb);
            if (fl & 1u) u8N = *(const unsigned*)((const uint8_t*)mask + nb);
            else         mN  = *(const uint4*)((const unsigned*)mask + nb);
        }
        int row = rowBase + ty * 8 + i;
        size_t base = (size_t)row * NSQ + colOff;
        float mv[4];
        if (fl & 2u) {           // float32 mask: compare as float
            mv[0] = (__uint_as_float(mC.x) != 0.f) ? 1.f : 0.f;
            mv[1] = (__uint_as_float(mC.y) != 0.f) ? 1.f : 0.f;
            mv[2] = (__uint_as_float(mC.z) != 0.f) ? 1.f : 0.f;
            mv[3] = (__uint_as_float(mC.w) != 0.f) ? 1.f : 0.f;
        } else if (fl & 1u) {    // uint8 packed bool
            mv[0] = (u8C & 0x000000ffu) ? 1.f : 0.f;
            mv[1] = (u8C & 0x0000ff00u) ? 1.f : 0.f;
            mv[2] = (u8C & 0x00ff0000u) ? 1.f : 0.f;
            mv[3] = (u8C & 0xff000000u) ? 1.f : 0.f;
        } else {                 // int32
            mv[0] = mC.x ? 1.f : 0.f;
            mv[1] = mC.y ? 1.f : 0.f;
            mv[2] = mC.z ? 1.f : 0.f;
            mv[3] = mC.w ? 1.f : 0.f;
        }
        float vv[4] = {vC.x, vC.y, vC.z, vC.w};
        float bb[4] = {bC.x, bC.y, bC.z, bC.w};
        float e[4];
        float rs = 0.f;
#pragma unroll
        for (int j = 0; j < 4; ++j) {
            float x  = acc[i][j] + bb[j];
            float sg = 1.0f / (1.0f + __expf(-x));
            float ev = vv[j] * sg;
            float r  = mv[j] * __expf(ev);
            e[j] = r; rs += r;
        }
        *(float4*)(out + base) = make_float4(e[0], e[1], e[2], e[3]);
        rs += __shfl_xor(rs, 1);
        rs += __shfl_xor(rs, 2);
        rs += __shfl_xor(rs, 4);
        rs += __shfl_xor(rs, 8);
        if (tx == 0) atomicAdd(&rowsum[row], rs);
        vC = vN; bC = bN; mC = mN; u8C = u8N;
    }
}

// ---------------------------------------------------------------------------
// normalize: A = ee / (rowsum + 1e-6). One row per block; 8 independent
// float4 loads per thread so latency is hidden.
__global__ __launch_bounds__(256) void k_norm(float* __restrict__ out,
                                              const float* __restrict__ rowsum) {
    int row = blockIdx.x;
    int t = threadIdx.x;
    float inv = 1.0f / (rowsum[row] + 1e-6f);
    float4* p = (float4*)out + (size_t)row * 2048;
    float4 v[8];
#pragma unroll
    for (int q = 0; q < 8; ++q) v[q] = p[t + q * 256];
#pragma unroll
    for (int q = 0; q < 8; ++q) {
        v[q].x *= inv; v[q].y *= inv; v[q].z *= inv; v[q].w *= inv;
        p[t + q * 256] = v[q];
    }
}

// ---------------------------------------------------------------------------
extern "C" void kernel_launch(void* const* d_in, const int* in_sizes, int n_in,
                              void* d_out, int out_size, void* d_ws, size_t ws_size,
                              hipStream_t stream) {
    const float* H    = (const float*)d_in[0];  // [8192,64,64]
    const float* w1   = (const float*)d_in[1];  // [64]
    const float* W2   = (const float*)d_in[2];  // [64,64]
    const float* w3   = (const float*)d_in[3];  // [64]
    const float* V    = (const float*)d_in[4];  // [8192,8192]
    const float* Bm   = (const float*)d_in[5];  // [8192,8192]
    const void*  mask = d_in[6];                // [8192,8192] dtype detected at runtime
    float* out = (float*)d_out;
    float* ws  = (float*)d_ws;

    float*    X1T    = ws + WS_X1T;
    float*    X2T    = ws + WS_X2T;
    float*    rowsum = ws + WS_RS;
    float*    w2t    = ws + WS_W2T;
    unsigned* flag   = (unsigned*)(ws + WS_FLAG);

    k_init   <<<32,            256, 0, stream>>>(W2, ws);
    k_detect <<<1024,          256, 0, stream>>>((const uint4*)mask, flag);
    k_prep   <<<2048,          256, 0, stream>>>(H, w1, w3, w2t, X1T, X2T);
    k_main   <<<dim3(128, 64), 256, 0, stream>>>(X1T, X2T, V, Bm, mask, flag, out, rowsum);
    k_norm   <<<8192,          256, 0, stream>>>(out, rowsum);
}

// Round 4
// 938.189 us; speedup vs baseline: 1.0144x; 1.0144x over previous
//
#include <hip/hip_runtime.h>
#include <stdint.h>

// Problem constants: N_S=8192, N_H=64, C=64
#define NSQ 8192

typedef __attribute__((ext_vector_type(8)))  short short8;   // 8 bf16 (4 VGPRs)
typedef __attribute__((ext_vector_type(16))) float f32x16;   // MFMA 32x32 C/D

// Workspace layout. Packed MFMA fragments first (uint4 units), then floats.
// X1hi/X1lo/X2hi/X2lo: each 65536 uint4 = 1 MB (fragment order, see k_prep).
#define WS_RS   1048576u                  // rowsum [8192] (float offset)
#define WS_W2T  (1048576u + 8192u)        // W2^T [64][64]
#define WS_FLAG (1048576u + 8192u + 4096u)

// ---------------------------------------------------------------------------
// init: zero rowsum + flag, build W2T (W2T[h*64+i] = W2[i*64+h])
__global__ __launch_bounds__(256) void k_init(const float* __restrict__ W2,
                                              float* __restrict__ ws) {
    int t = threadIdx.x, b = blockIdx.x;
    ws[WS_RS + b * 256 + t] = 0.0f;   // 32 blocks x 256 = 8192
    if (b == 0) {
#pragma unroll
        for (int q = 0; q < 16; ++q) {
            int e = q * 256 + t;
            int i = e >> 6, h = e & 63;
            ws[WS_W2T + h * 64 + i] = W2[i * 64 + h];
        }
        if (t == 0) ((unsigned*)ws)[WS_FLAG] = 0u;
    }
}

// ---------------------------------------------------------------------------
// detect mask dtype from a 4 MB sample.
// f32 mask -> words == 0x3f800000 ; u8 packed -> some word > 1 ; i32 -> {0,1}
__global__ __launch_bounds__(256) void k_detect(const uint4* __restrict__ m,
                                                unsigned* __restrict__ flag) {
    __shared__ unsigned bf;
    int t = threadIdx.x;
    if (t == 0) bf = 0u;
    __syncthreads();
    size_t idx = (size_t)blockIdx.x * 256 + t;
    uint4 v = m[idx];
    unsigned a[4] = {v.x, v.y, v.z, v.w};
    unsigned lf = 0u;
#pragma unroll
    for (int q = 0; q < 4; ++q) {
        if (a[q] == 0x3f800000u) lf |= 2u;
        else if (a[q] > 1u)      lf |= 1u;
    }
    if (lf) atomicOr(&bf, lf);
    __syncthreads();
    if (t == 0 && bf) atomicOr(flag, bf);
}

// ---------------------------------------------------------------------------
// round-to-nearest-even fp32 -> bf16 split: x ~= hi + lo
__device__ inline void bf16split(float x, unsigned short& hi, unsigned short& lo) {
    unsigned u = __float_as_uint(x);
    unsigned r = (u + 0x7fffu + ((u >> 16) & 1u)) >> 16;
    hi = (unsigned short)r;
    float res = x - __uint_as_float(r << 16);
    unsigned u2 = __float_as_uint(res);
    unsigned r2 = (u2 + 0x7fffu + ((u2 >> 16) & 1u)) >> 16;
    lo = (unsigned short)r2;
}

// ---------------------------------------------------------------------------
// fused prep: reads H' ONCE (float4), computes
//   Y[s,h]  = sum_c H'[s,c,h]*w1[c]
//   X1[s,i] = sum_h Y[s,h]*W2[i,h]
//   X2[s,c] = sum_h H'[s,c,h]*w3[h]
// then packs X1/X2 rows into split-bf16 MFMA fragment order:
//   chunk (T=s>>5, kk, h, r=s&31) = 8 bf16 of X[s][kk*16+h*8 .. +8]
//   stored at uint4 index (T*4+kk)*64 + h*32 + r
// so k_main's lane l reads its 32x32x16 A/B fragment at ((T*4+kk)*64 + l).
__global__ __launch_bounds__(256) void k_prep(const float* __restrict__ H,
                                              const float* __restrict__ w1,
                                              const float* __restrict__ w3,
                                              const float* __restrict__ w2t,
                                              uint4* __restrict__ X1hi,
                                              uint4* __restrict__ X1lo,
                                              uint4* __restrict__ X2hi,
                                              uint4* __restrict__ X2lo) {
    __shared__ float ylds[4][64];
    __shared__ float x1b[4][64];
    __shared__ float x2b[4][64];
    int t = threadIdx.x;
    int sl = t >> 6, l = t & 63;
    int cq = l >> 4, hq = l & 15;
    size_t s = (size_t)blockIdx.x * 4 + sl;
    const float* hp = H + s * 4096;
    float4 w3q = *(const float4*)(w3 + hq * 4);
    float4 yacc = make_float4(0.f, 0.f, 0.f, 0.f);
    float x2p[16];
#pragma unroll
    for (int cc = 0; cc < 16; ++cc) {
        int c = cq * 16 + cc;
        float4 hv = *(const float4*)(hp + c * 64 + hq * 4);
        float wc = w1[c];
        yacc.x = fmaf(hv.x, wc, yacc.x);
        yacc.y = fmaf(hv.y, wc, yacc.y);
        yacc.z = fmaf(hv.z, wc, yacc.z);
        yacc.w = fmaf(hv.w, wc, yacc.w);
        x2p[cc] = hv.x * w3q.x + hv.y * w3q.y + hv.z * w3q.z + hv.w * w3q.w;
    }
#pragma unroll
    for (int cc = 0; cc < 16; ++cc) {
        float v = x2p[cc];
        v += __shfl_xor(v, 1);
        v += __shfl_xor(v, 2);
        v += __shfl_xor(v, 4);
        v += __shfl_xor(v, 8);
        x2p[cc] = v;
    }
    if (hq == 0) {
#pragma unroll
        for (int cc = 0; cc < 16; ++cc) x2b[sl][cq * 16 + cc] = x2p[cc];
    }
    yacc.x += __shfl_xor(yacc.x, 16); yacc.x += __shfl_xor(yacc.x, 32);
    yacc.y += __shfl_xor(yacc.y, 16); yacc.y += __shfl_xor(yacc.y, 32);
    yacc.z += __shfl_xor(yacc.z, 16); yacc.z += __shfl_xor(yacc.z, 32);
    yacc.w += __shfl_xor(yacc.w, 16); yacc.w += __shfl_xor(yacc.w, 32);
    if (cq == 0) *(float4*)&ylds[sl][hq * 4] = yacc;
    __syncthreads();
    float a1 = 0.f;
#pragma unroll
    for (int h = 0; h < 64; ++h) a1 = fmaf(ylds[sl][h], w2t[h * 64 + l], a1);
    x1b[sl][l] = a1;
    __syncthreads();

    // pack phase: threads 0..63: 4 s-slots x {X1,X2} x 8 k-groups
    if (t < 64) {
        int sl2 = t >> 4;
        int q   = t & 15;
        int mat = q >> 3;       // 0 = X1, 1 = X2
        int kg  = q & 7;        // k-group of 8
        const float* src = mat ? x2b[sl2] : x1b[sl2];
        unsigned short hi8[8], lo8[8];
#pragma unroll
        for (int j = 0; j < 8; ++j) bf16split(src[kg * 8 + j], hi8[j], lo8[j]);
        int sg = blockIdx.x * 4 + sl2;
        int T = sg >> 5, r = sg & 31;
        int kk = kg >> 1, h = kg & 1;
        unsigned ci = (unsigned)((T * 4 + kk) * 64 + h * 32 + r);
        uint4 hv, lv;
        hv.x = (unsigned)hi8[0] | ((unsigned)hi8[1] << 16);
        hv.y = (unsigned)hi8[2] | ((unsigned)hi8[3] << 16);
        hv.z = (unsigned)hi8[4] | ((unsigned)hi8[5] << 16);
        hv.w = (unsigned)hi8[6] | ((unsigned)hi8[7] << 16);
        lv.x = (unsigned)lo8[0] | ((unsigned)lo8[1] << 16);
        lv.y = (unsigned)lo8[2] | ((unsigned)lo8[3] << 16);
        lv.z = (unsigned)lo8[4] | ((unsigned)lo8[5] << 16);
        lv.w = (unsigned)lo8[6] | ((unsigned)lo8[7] << 16);
        if (mat) { X2hi[ci] = hv; X2lo[ci] = lv; }
        else     { X1hi[ci] = hv; X1lo[ci] = lv; }
    }
}

// ---------------------------------------------------------------------------
// main: 128x128 tile per block, 4 independent waves (NO LDS, NO barriers).
// Wave w: rows [by*128 + w*32, +32) x all 128 cols = 4 MFMA 32x32 tiles.
// GEMM: split-bf16, 3 MFMAs per (tile,kstep): hi*lo + lo*hi + hi*hi.
// Operands read straight from L2-resident packed fragments (coalesced 1KB/inst).
// Epilogue addresses the MFMA C-layout directly:
//   col = colBase + ct*32 + (l&31), row = rowStrip + (g&3) + 8*(g>>2) + 4*(l>>5)
// each (g,ct) access = 2 x 128B segments. Pipelined g+1 prefetch.
__global__ __launch_bounds__(256, 4) void k_main(const uint4* __restrict__ X1hi,
                                                 const uint4* __restrict__ X1lo,
                                                 const uint4* __restrict__ X2hi,
                                                 const uint4* __restrict__ X2lo,
                                                 const float* __restrict__ V,
                                                 const float* __restrict__ Bm,
                                                 const void* __restrict__ mask,
                                                 const unsigned* __restrict__ flag,
                                                 float* __restrict__ out,
                                                 float* __restrict__ rowsum) {
    int t = threadIdx.x;
    int w = t >> 6, l = t & 63;

    f32x16 acc[4];
#pragma unroll
    for (int ct = 0; ct < 4; ++ct)
#pragma unroll
        for (int e = 0; e < 16; ++e) acc[ct][e] = 0.f;

    const short8* A_hi = (const short8*)X1hi;
    const short8* A_lo = (const short8*)X1lo;
    const short8* B_hi = (const short8*)X2hi;
    const short8* B_lo = (const short8*)X2lo;
    int aT = blockIdx.y * 4 + w;   // row-tile index
    int bT = blockIdx.x * 4;       // first col-tile index

#pragma unroll
    for (int kk = 0; kk < 4; ++kk) {
        short8 ah = A_hi[(aT * 4 + kk) * 64 + l];
        short8 al = A_lo[(aT * 4 + kk) * 64 + l];
#pragma unroll
        for (int ct = 0; ct < 4; ++ct) {
            int bi = ((bT + ct) * 4 + kk) * 64 + l;
            short8 bh = B_hi[bi];
            short8 bl = B_lo[bi];
            acc[ct] = __builtin_amdgcn_mfma_f32_32x32x16_bf16(ah, bl, acc[ct], 0, 0, 0);
            acc[ct] = __builtin_amdgcn_mfma_f32_32x32x16_bf16(al, bh, acc[ct], 0, 0, 0);
            acc[ct] = __builtin_amdgcn_mfma_f32_32x32x16_bf16(ah, bh, acc[ct], 0, 0, 0);
        }
    }

    unsigned fl = *flag;
    int h = l >> 5, c = l & 31;
    int rstrip = blockIdx.y * 128 + w * 32 + h * 4;
    size_t colB = (size_t)blockIdx.x * 128 + c;

    float pv[4], pb[4], pm[4];
    float nv[4], nb[4], nm[4];

#define LOADG(g, av, ab, am)                                                     \
    {                                                                            \
        int row_ = rstrip + ((g) & 3) + (((g) >> 2) << 3);                       \
        size_t base_ = (size_t)row_ * NSQ + colB;                                \
        _Pragma("unroll")                                                        \
        for (int ct_ = 0; ct_ < 4; ++ct_) {                                      \
            av[ct_] = V[base_ + ct_ * 32];                                       \
            ab[ct_] = Bm[base_ + ct_ * 32];                                      \
        }                                                                        \
        if (fl & 2u) {                                                           \
            _Pragma("unroll")                                                    \
            for (int ct_ = 0; ct_ < 4; ++ct_)                                    \
                am[ct_] = (((const float*)mask)[base_ + ct_ * 32] != 0.f) ? 1.f : 0.f; \
        } else if (fl & 1u) {                                                    \
            _Pragma("unroll")                                                    \
            for (int ct_ = 0; ct_ < 4; ++ct_)                                    \
                am[ct_] = ((const uint8_t*)mask)[base_ + ct_ * 32] ? 1.f : 0.f;  \
        } else {                                                                 \
            _Pragma("unroll")                                                    \
            for (int ct_ = 0; ct_ < 4; ++ct_)                                    \
                am[ct_] = ((const int*)mask)[base_ + ct_ * 32] ? 1.f : 0.f;      \
        }                                                                        \
    }

    LOADG(0, pv, pb, pm);
#pragma unroll
    for (int g = 0; g < 16; ++g) {
        if (g < 15) LOADG(g + 1, nv, nb, nm);
        int row = rstrip + (g & 3) + ((g >> 2) << 3);
        size_t base = (size_t)row * NSQ + colB;
        float rsg = 0.f;
#pragma unroll
        for (int ct = 0; ct < 4; ++ct) {
            float x  = acc[ct][g] + pb[ct];
            float sg = 1.0f / (1.0f + __expf(-x));
            float e  = pm[ct] * __expf(pv[ct] * sg);
            out[base + ct * 32] = e;
            rsg += e;
        }
        rsg += __shfl_xor(rsg, 1);
        rsg += __shfl_xor(rsg, 2);
        rsg += __shfl_xor(rsg, 4);
        rsg += __shfl_xor(rsg, 8);
        rsg += __shfl_xor(rsg, 16);
        if (c == 0) atomicAdd(&rowsum[row], rsg);
#pragma unroll
        for (int ct = 0; ct < 4; ++ct) { pv[ct] = nv[ct]; pb[ct] = nb[ct]; pm[ct] = nm[ct]; }
    }
#undef LOADG
}

// ---------------------------------------------------------------------------
// normalize: A = ee / (rowsum + 1e-6). One row per block; 8 independent
// float4 loads per thread so latency is hidden.
__global__ __launch_bounds__(256) void k_norm(float* __restrict__ out,
                                              const float* __restrict__ rowsum) {
    int row = blockIdx.x;
    int t = threadIdx.x;
    float inv = 1.0f / (rowsum[row] + 1e-6f);
    float4* p = (float4*)out + (size_t)row * 2048;
    float4 v[8];
#pragma unroll
    for (int q = 0; q < 8; ++q) v[q] = p[t + q * 256];
#pragma unroll
    for (int q = 0; q < 8; ++q) {
        v[q].x *= inv; v[q].y *= inv; v[q].z *= inv; v[q].w *= inv;
        p[t + q * 256] = v[q];
    }
}

// ---------------------------------------------------------------------------
extern "C" void kernel_launch(void* const* d_in, const int* in_sizes, int n_in,
                              void* d_out, int out_size, void* d_ws, size_t ws_size,
                              hipStream_t stream) {
    const float* H    = (const float*)d_in[0];  // [8192,64,64]
    const float* w1   = (const float*)d_in[1];  // [64]
    const float* W2   = (const float*)d_in[2];  // [64,64]
    const float* w3   = (const float*)d_in[3];  // [64]
    const float* V    = (const float*)d_in[4];  // [8192,8192]
    const float* Bm   = (const float*)d_in[5];  // [8192,8192]
    const void*  mask = d_in[6];                // [8192,8192] dtype detected at runtime
    float* out = (float*)d_out;
    float* ws  = (float*)d_ws;

    uint4* X1hi = (uint4*)ws;                   // 65536 uint4 each (1 MB)
    uint4* X1lo = X1hi + 65536;
    uint4* X2hi = X1hi + 131072;
    uint4* X2lo = X1hi + 196608;
    float*    rowsum = ws + WS_RS;
    float*    w2t    = ws + WS_W2T;
    unsigned* flag   = (unsigned*)(ws + WS_FLAG);

    k_init   <<<32,           256, 0, stream>>>(W2, ws);
    k_detect <<<1024,         256, 0, stream>>>((const uint4*)mask, flag);
    k_prep   <<<2048,         256, 0, stream>>>(H, w1, w3, w2t, X1hi, X1lo, X2hi, X2lo);
    k_main   <<<dim3(64, 64), 256, 0, stream>>>(X1hi, X1lo, X2hi, X2lo,
                                                V, Bm, mask, flag, out, rowsum);
    k_norm   <<<8192,         256, 0, stream>>>(out, rowsum);
}